// Round 4
// baseline (86.947 us; speedup 1.0000x reference)
//
#include <hip/hip_runtime.h>

#define SIREN_K 4
#define SIREN_H 32
#define SIREN_C 512
#define SIREN_C4 128   // C / 4
#define OMEGA0 30.0f

typedef float f32x4 __attribute__((ext_vector_type(4)));

// ---------------------------------------------------------------------------
// Fused kernel: every block (1) recomputes the tiny SIREN filter table
// [K][C] into LDS (~65K FMA, weights are L2-resident), then (2) streams its
// grid-stride slice of the depthwise strided conv:
//   out[bl*512+c] = sum_k x[(4*bl+k)*512 + c] * ker[k][c]
// f32x4 view: out4[bl*128+c4] = sum_k x4[bl*512 + k*128 + c4] * ker4[k][c4]
// blockDim=256 (multiple of 128) -> c4 = tid & 127 is thread-invariant, so
// the 4 weight vectors load once from LDS into registers.
// Output uses nontemporal stores: out is write-once; keep the 256 MiB L3
// free to retain x across graph replays.
// ---------------------------------------------------------------------------
__global__ void __launch_bounds__(256) siren_dwconv_fused(
    const f32x4* __restrict__ x4,
    const float* __restrict__ w0, const float* __restrict__ b0,
    const float* __restrict__ w1, const float* __restrict__ b1,
    const float* __restrict__ w2, const float* __restrict__ b2,
    const float* __restrict__ w3, const float* __restrict__ b3,
    f32x4* __restrict__ out4, int total4)
{
    __shared__ float hA[SIREN_K][SIREN_H];
    __shared__ float hB[SIREN_K][SIREN_H];
    __shared__ float kerS[SIREN_K][SIREN_C];   // 8 KiB

    const int tid = threadIdx.x;

    // ---- stage 0: h = sin(omega0 * pos * w0 + b0), 128 threads ----
    if (tid < SIREN_K * SIREN_H) {
        int k = tid >> 5, j = tid & 31;
        float pos = -1.0f + (2.0f / (float)(SIREN_K - 1)) * (float)k;
        if (k == SIREN_K - 1) pos = 1.0f;   // linspace endpoint exact
        pos *= OMEGA0;
        hA[k][j] = sinf(pos * w0[j] + b0[j]);
    }
    __syncthreads();

    // ---- stage 1 ----
    if (tid < SIREN_K * SIREN_H) {
        int k = tid >> 5, j = tid & 31;
        float s = b1[j];
        #pragma unroll
        for (int i = 0; i < SIREN_H; ++i) s += hA[k][i] * w1[j * SIREN_H + i];
        hB[k][j] = sinf(s);
    }
    __syncthreads();

    // ---- stage 2 ----
    if (tid < SIREN_K * SIREN_H) {
        int k = tid >> 5, j = tid & 31;
        float s = b2[j];
        #pragma unroll
        for (int i = 0; i < SIREN_H; ++i) s += hB[k][i] * w2[j * SIREN_H + i];
        hA[k][j] = sinf(s);
    }
    __syncthreads();

    // ---- stage 3: ker[k][c] = h @ w3.T + b3 ----
    // Block has 256 threads; C=512 -> each thread handles TWO channels.
    for (int c = tid; c < SIREN_C; c += 256) {
        const f32x4* w3v = (const f32x4*)(w3 + c * SIREN_H);  // 8 vec4s
        f32x4 wrow[SIREN_H / 4];
        #pragma unroll
        for (int q = 0; q < SIREN_H / 4; ++q) wrow[q] = w3v[q];
        #pragma unroll
        for (int k = 0; k < SIREN_K; ++k) {
            float s = b3[c];
            #pragma unroll
            for (int q = 0; q < SIREN_H / 4; ++q) {
                s += hA[k][4*q+0] * wrow[q].x + hA[k][4*q+1] * wrow[q].y
                   + hA[k][4*q+2] * wrow[q].z + hA[k][4*q+3] * wrow[q].w;
            }
            kerS[k][c] = s;
        }
    }
    __syncthreads();

    // ---- conv weights -> registers (c4 is thread-invariant) ----
    const int c4 = tid & (SIREN_C4 - 1);
    const f32x4 wv0 = ((const f32x4*)&kerS[0][0])[c4];
    const f32x4 wv1 = ((const f32x4*)&kerS[1][0])[c4];
    const f32x4 wv2 = ((const f32x4*)&kerS[2][0])[c4];
    const f32x4 wv3 = ((const f32x4*)&kerS[3][0])[c4];

    // ---- streaming depthwise conv ----
    int idx = blockIdx.x * 256 + tid;
    const int gstride = gridDim.x * 256;   // multiple of 128
    #pragma unroll 2
    for (; idx < total4; idx += gstride) {
        const int bl = idx >> 7;           // idx / 128
        const f32x4* xp = x4 + bl * (4 * SIREN_C4) + c4;
        const f32x4 a = xp[0 * SIREN_C4];
        const f32x4 b = xp[1 * SIREN_C4];
        const f32x4 c = xp[2 * SIREN_C4];
        const f32x4 d = xp[3 * SIREN_C4];
        f32x4 o = a * wv0 + b * wv1 + c * wv2 + d * wv3;
        __builtin_nontemporal_store(o, &out4[idx]);
    }
}

extern "C" void kernel_launch(void* const* d_in, const int* in_sizes, int n_in,
                              void* d_out, int out_size, void* d_ws, size_t ws_size,
                              hipStream_t stream) {
    // Input order (setup_inputs): x, w0, b0, w1, b1, w2, b2, w3, b3, target_len
    const float* x  = (const float*)d_in[0];
    const float* w0 = (const float*)d_in[1];
    const float* b0 = (const float*)d_in[2];
    const float* w1 = (const float*)d_in[3];
    const float* b1 = (const float*)d_in[4];
    const float* w2 = (const float*)d_in[5];
    const float* b2 = (const float*)d_in[6];
    const float* w3 = (const float*)d_in[7];
    const float* b3 = (const float*)d_in[8];

    const int total4 = out_size / 4;       // 4,194,304 f32x4s
    const int blocks = 4096;               // 4 grid-stride iters/thread
    siren_dwconv_fused<<<blocks, 256, 0, stream>>>(
        (const f32x4*)x, w0, b0, w1, b1, w2, b2, w3, b3,
        (f32x4*)d_out, total4);
}

// Round 5
// 69.948 us; speedup vs baseline: 1.2430x; 1.2430x over previous
//
#include <hip/hip_runtime.h>

#define SIREN_K 4
#define SIREN_H 32
#define SIREN_C 512
#define SIREN_C4 128   // C / 4
#define OMEGA0 30.0f

typedef float f32x4 __attribute__((ext_vector_type(4)));

// ---------------------------------------------------------------------------
// Kernel 1: build the [K][C] SIREN filter table (tiny MLP, one block, 512 thr).
// ---------------------------------------------------------------------------
__global__ void siren_table_kernel(const float* __restrict__ w0, const float* __restrict__ b0,
                                   const float* __restrict__ w1, const float* __restrict__ b1,
                                   const float* __restrict__ w2, const float* __restrict__ b2,
                                   const float* __restrict__ w3, const float* __restrict__ b3,
                                   float* __restrict__ ker /* [K][C] */) {
    __shared__ float bufA[SIREN_K][SIREN_H];
    __shared__ float bufB[SIREN_K][SIREN_H];
    const int tid = threadIdx.x;

    if (tid < SIREN_K * SIREN_H) {
        int k = tid >> 5, j = tid & 31;
        float pos = -1.0f + (2.0f / (float)(SIREN_K - 1)) * (float)k;
        if (k == SIREN_K - 1) pos = 1.0f;  // linspace endpoint exact
        pos *= OMEGA0;
        bufA[k][j] = sinf(pos * w0[j] + b0[j]);
    }
    __syncthreads();

    if (tid < SIREN_K * SIREN_H) {
        int k = tid >> 5, j = tid & 31;
        float s = b1[j];
        #pragma unroll
        for (int i = 0; i < SIREN_H; ++i) s += bufA[k][i] * w1[j * SIREN_H + i];
        bufB[k][j] = sinf(s);
    }
    __syncthreads();

    if (tid < SIREN_K * SIREN_H) {
        int k = tid >> 5, j = tid & 31;
        float s = b2[j];
        #pragma unroll
        for (int i = 0; i < SIREN_H; ++i) s += bufB[k][i] * w2[j * SIREN_H + i];
        bufA[k][j] = sinf(s);
    }
    __syncthreads();

    const int c = tid;  // 512 threads, one channel each
    if (c < SIREN_C) {
        const f32x4* w3v = (const f32x4*)(w3 + c * SIREN_H);
        f32x4 wrow[SIREN_H / 4];
        #pragma unroll
        for (int q = 0; q < SIREN_H / 4; ++q) wrow[q] = w3v[q];
        #pragma unroll
        for (int k = 0; k < SIREN_K; ++k) {
            float s = b3[c];
            #pragma unroll
            for (int q = 0; q < SIREN_H / 4; ++q) {
                s += bufA[k][4*q+0] * wrow[q].x + bufA[k][4*q+1] * wrow[q].y
                   + bufA[k][4*q+2] * wrow[q].z + bufA[k][4*q+3] * wrow[q].w;
            }
            ker[k * SIREN_C + c] = s;
        }
    }
}

// ---------------------------------------------------------------------------
// Kernel 2: depthwise strided conv — exact grid, zero loop, 2 outputs/thread.
// out4[idx] = sum_k x4[(idx>>7)*512 + k*128 + (idx&127)] * ker4[k*128 + (idx&127)]
// 8192 blocks x 256 threads; thread handles idx0 = bid*512+tid and idx0+256.
// (idx0+256) keeps the same c4, so one weight set serves both outputs.
// 8 independent global loads in flight per thread (128 B MLP depth).
// ---------------------------------------------------------------------------
__global__ void __launch_bounds__(256) dwconv_kernel(const f32x4* __restrict__ x4,
                                                     const f32x4* __restrict__ ker4,
                                                     f32x4* __restrict__ out4) {
    const int tid = threadIdx.x;
    const int idx0 = blockIdx.x * 512 + tid;
    const int idx1 = idx0 + 256;
    const int c4 = tid & (SIREN_C4 - 1);

    const int bl0 = idx0 >> 7;
    const int bl1 = idx1 >> 7;
    const f32x4* xp0 = x4 + bl0 * (4 * SIREN_C4) + c4;
    const f32x4* xp1 = x4 + bl1 * (4 * SIREN_C4) + c4;

    // 8 independent loads — issue all before any use
    const f32x4 a0 = xp0[0 * SIREN_C4];
    const f32x4 b0 = xp0[1 * SIREN_C4];
    const f32x4 c0 = xp0[2 * SIREN_C4];
    const f32x4 d0 = xp0[3 * SIREN_C4];
    const f32x4 a1 = xp1[0 * SIREN_C4];
    const f32x4 b1 = xp1[1 * SIREN_C4];
    const f32x4 c1 = xp1[2 * SIREN_C4];
    const f32x4 d1 = xp1[3 * SIREN_C4];

    const f32x4 wv0 = ker4[0 * SIREN_C4 + c4];
    const f32x4 wv1 = ker4[1 * SIREN_C4 + c4];
    const f32x4 wv2 = ker4[2 * SIREN_C4 + c4];
    const f32x4 wv3 = ker4[3 * SIREN_C4 + c4];

    out4[idx0] = a0 * wv0 + b0 * wv1 + c0 * wv2 + d0 * wv3;
    out4[idx1] = a1 * wv0 + b1 * wv1 + c1 * wv2 + d1 * wv3;
}

extern "C" void kernel_launch(void* const* d_in, const int* in_sizes, int n_in,
                              void* d_out, int out_size, void* d_ws, size_t ws_size,
                              hipStream_t stream) {
    // Input order (setup_inputs): x, w0, b0, w1, b1, w2, b2, w3, b3, target_len
    const float* x  = (const float*)d_in[0];
    const float* w0 = (const float*)d_in[1];
    const float* b0 = (const float*)d_in[2];
    const float* w1 = (const float*)d_in[3];
    const float* b1 = (const float*)d_in[4];
    const float* w2 = (const float*)d_in[5];
    const float* b2 = (const float*)d_in[6];
    const float* w3 = (const float*)d_in[7];
    const float* b3 = (const float*)d_in[8];

    float* ker = (float*)d_ws;  // K*C floats = 8 KiB

    siren_table_kernel<<<1, 512, 0, stream>>>(w0, b0, w1, b1, w2, b2, w3, b3, ker);

    const int total4 = out_size / 4;        // 4,194,304 f32x4 outputs
    const int blocks = total4 / 512;        // 8192, exact (no tail)
    dwconv_kernel<<<blocks, 256, 0, stream>>>((const f32x4*)x, (const f32x4*)ker,
                                              (f32x4*)d_out);
}